// Round 6
// baseline (370.098 us; speedup 1.0000x reference)
//
#include <hip/hip_runtime.h>
#include <hip/hip_bf16.h>

typedef unsigned short u16;
typedef __bf16 bf16x8 __attribute__((ext_vector_type(8)));
typedef float f32x4 __attribute__((ext_vector_type(4)));

#define L_SEQ 4096
#define CDIM  1024
#define NH    16
#define HD    64
#define N_QKV 3072
#define ATT_STRIDE 80   // LDS row stride (halfwords): 160 B, keeps bf16x8 16-B aligned

static __device__ __forceinline__ u16 f2bf(float f) {
    union { float f; unsigned int i; } v; v.f = f;
    unsigned int u = v.i;
    return (u16)((u + 0x7fffu + ((u >> 16) & 1u)) >> 16);   // RNE
}

static __device__ __forceinline__ f32x4 mfma16x16x32(bf16x8 a, bf16x8 b, f32x4 c) {
    return __builtin_amdgcn_mfma_f32_16x16x32_bf16(a, b, c, 0, 0, 0);
}

// ---------------- x (fp32) -> bf16, 8 elems/thread ----------------
__global__ __launch_bounds__(256) void k_cast_x(const float* __restrict__ src,
                                                u16* __restrict__ dst, int n8) {
    int i = blockIdx.x * 256 + threadIdx.x;
    if (i >= n8) return;
    const float4* s = (const float4*)(src + (size_t)i * 8);
    float4 a = s[0], b = s[1];
    u16 o[8] = { f2bf(a.x), f2bf(a.y), f2bf(a.z), f2bf(a.w),
                 f2bf(b.x), f2bf(b.y), f2bf(b.z), f2bf(b.w) };
    *(uint4*)(dst + (size_t)i * 8) = *(uint4*)o;
}

// ---------------- transpose + cast: src fp32 [R][C] -> dst bf16 [C][R] ----------------
__global__ __launch_bounds__(256) void k_transpose_cast(const float* __restrict__ src,
                                                        u16* __restrict__ dst,
                                                        int R, int C) {
    __shared__ u16 tile[32][33];
    int c0 = blockIdx.x * 32, r0 = blockIdx.y * 32;
    int tx = threadIdx.x & 31, ty = threadIdx.x >> 5;   // 32 x 8
#pragma unroll
    for (int i = 0; i < 32; i += 8)
        tile[ty + i][tx] = f2bf(src[(size_t)(r0 + ty + i) * C + c0 + tx]);
    __syncthreads();
#pragma unroll
    for (int i = 0; i < 32; i += 8)
        dst[(size_t)(c0 + ty + i) * R + r0 + tx] = tile[tx][ty + i];
}

// ---------------- V transpose (bf16): qkv[:, 2C + h*64 + d] -> vt[h*64+d][key] ----------------
__global__ __launch_bounds__(256) void k_transpose_v(const u16* __restrict__ qkv,
                                                     u16* __restrict__ vt) {
    __shared__ u16 tile[32][33];
    int k0 = blockIdx.x * 32, d0 = blockIdx.y * 32, h = blockIdx.z;
    int tx = threadIdx.x & 31, ty = threadIdx.x >> 5;
#pragma unroll
    for (int i = 0; i < 32; i += 8)
        tile[ty + i][tx] = qkv[(size_t)(k0 + ty + i) * N_QKV + 2 * CDIM + h * HD + d0 + tx];
    __syncthreads();
#pragma unroll
    for (int i = 0; i < 32; i += 8)
        vt[(size_t)(h * HD + d0 + ty + i) * L_SEQ + k0 + tx] = tile[tx][ty + i];
}

// ------- GEMM: C[M][N] = A[M][K] @ Bt[N][K]^T + bias[N]; A,Bt bf16; bias fp32;
//         OutT selects epilogue dtype (u16 -> bf16 store, float -> fp32 store) -------
template <typename OutT>
__global__ __launch_bounds__(256) void k_gemm_bt(const u16* __restrict__ A,
                                                 const u16* __restrict__ Bt,
                                                 const float* __restrict__ bias,
                                                 OutT* __restrict__ Cmat,
                                                 int M, int N, int K) {
    __shared__ alignas(16) u16 As[128 * 32];
    __shared__ alignas(16) u16 Bs[128 * 32];
    int t = threadIdx.x;
    int n0 = blockIdx.x * 128, m0 = blockIdx.y * 128;
    int l = t & 63, w = t >> 6;
    int wm = (w >> 1) * 64, wn = (w & 1) * 64;
    int lr = l & 15, lq = l >> 4;

    const f32x4 vzero = {0.f, 0.f, 0.f, 0.f};
    f32x4 acc[4][4];
#pragma unroll
    for (int mi = 0; mi < 4; mi++)
#pragma unroll
        for (int ni = 0; ni < 4; ni++) acc[mi][ni] = vzero;

    int ar = t >> 2;            // 0..63
    int ac = (t & 3) * 8;       // 0,8,16,24
    const u16* Ag = A + (size_t)(m0 + ar) * K + ac;
    const u16* Bg = Bt + (size_t)(n0 + ar) * K + ac;

    for (int k0 = 0; k0 < K; k0 += 32) {
        *(uint4*)&As[ar * 32 + ac]        = *(const uint4*)(Ag + k0);
        *(uint4*)&As[(ar + 64) * 32 + ac] = *(const uint4*)(Ag + (size_t)64 * K + k0);
        *(uint4*)&Bs[ar * 32 + ac]        = *(const uint4*)(Bg + k0);
        *(uint4*)&Bs[(ar + 64) * 32 + ac] = *(const uint4*)(Bg + (size_t)64 * K + k0);
        __syncthreads();

        bf16x8 af[4], bfr[4];
#pragma unroll
        for (int mi = 0; mi < 4; mi++)
            af[mi] = *(const bf16x8*)&As[(wm + mi * 16 + lr) * 32 + lq * 8];
#pragma unroll
        for (int ni = 0; ni < 4; ni++)
            bfr[ni] = *(const bf16x8*)&Bs[(wn + ni * 16 + lr) * 32 + lq * 8];
#pragma unroll
        for (int mi = 0; mi < 4; mi++)
#pragma unroll
            for (int ni = 0; ni < 4; ni++)
                acc[mi][ni] = mfma16x16x32(af[mi], bfr[ni], acc[mi][ni]);
        __syncthreads();
    }

#pragma unroll
    for (int ni = 0; ni < 4; ni++) {
        int col = n0 + wn + ni * 16 + lr;
        float bv = bias[col];
#pragma unroll
        for (int mi = 0; mi < 4; mi++) {
            int row = m0 + wm + mi * 16 + lq * 4;
#pragma unroll
            for (int r = 0; r < 4; r++) {
                float v = acc[mi][ni][r] + bv;
                if constexpr (sizeof(OutT) == 2)
                    Cmat[(size_t)(row + r) * N + col] = f2bf(v);
                else
                    Cmat[(size_t)(row + r) * N + col] = v;
            }
        }
    }
}

// ---------------- causal flash attention (MFMA; validated by agreement with naive) --------
// grid: (L/64 q-tiles, NH heads), 256 threads (4 waves; wave w owns 16 Q rows)
__global__ __launch_bounds__(256) void k_attn(const u16* __restrict__ qkv,
                                              const u16* __restrict__ vt,
                                              u16* __restrict__ attn) {
    __shared__ alignas(16) u16 Ks[64 * ATT_STRIDE];
    __shared__ alignas(16) u16 Vs[64 * ATT_STRIDE];
    __shared__ alignas(16) u16 Ps[4][16 * ATT_STRIDE];

    int t = threadIdx.x;
    int l = t & 63, w = t >> 6;
    int q0 = blockIdx.x * 64, h = blockIdx.y;
    int lr = l & 15, lq = l >> 4;

    // Q fragments (A-layout: m = lane&15 -> q row, k = quad*8+j -> d)
    bf16x8 aq[2];
    {
        const u16* Qg = qkv + (size_t)(q0 + w * 16 + lr) * N_QKV + h * HD + lq * 8;
        aq[0] = *(const bf16x8*)(Qg);
        aq[1] = *(const bf16x8*)(Qg + 32);
    }

    const f32x4 vzero = {0.f, 0.f, 0.f, 0.f};
    f32x4 o[4];
    float m_i[4], l_i[4];
#pragma unroll
    for (int r = 0; r < 4; r++) { m_i[r] = -1e30f; l_i[r] = 0.f; }
#pragma unroll
    for (int dt = 0; dt < 4; dt++) o[dt] = vzero;

    int row8 = t >> 3;          // 0..31
    int ch = (t & 7) * 8;       // 0..56
    int nkv = q0 / 64 + 1;

    for (int it = 0; it < nkv; ++it) {
        int k0 = it * 64;
        const u16* Kg = qkv + (size_t)(k0 + row8) * N_QKV + CDIM + h * HD + ch;
        *(uint4*)&Ks[row8 * ATT_STRIDE + ch]        = *(const uint4*)Kg;
        *(uint4*)&Ks[(row8 + 32) * ATT_STRIDE + ch] = *(const uint4*)(Kg + (size_t)32 * N_QKV);
        const u16* Vg = vt + (size_t)(h * HD + row8) * L_SEQ + k0 + ch;
        *(uint4*)&Vs[row8 * ATT_STRIDE + ch]        = *(const uint4*)Vg;
        *(uint4*)&Vs[(row8 + 32) * ATT_STRIDE + ch] = *(const uint4*)(Vg + (size_t)32 * L_SEQ);
        __syncthreads();

        // S = Q K^T (C-layout: row=(lq*4+r), col=nt*16+lr)
        f32x4 s[4];
#pragma unroll
        for (int nt = 0; nt < 4; nt++) s[nt] = vzero;
#pragma unroll
        for (int ks = 0; ks < 2; ks++)
#pragma unroll
            for (int nt = 0; nt < 4; nt++) {
                bf16x8 bk = *(const bf16x8*)&Ks[(nt * 16 + lr) * ATT_STRIDE + ks * 32 + lq * 8];
                s[nt] = mfma16x16x32(aq[ks], bk, s[nt]);
            }

        bool diag = (k0 == q0);
        float p[4][4];
#pragma unroll
        for (int nt = 0; nt < 4; nt++)
#pragma unroll
            for (int r = 0; r < 4; r++) {
                float v = s[nt][r] * 0.125f;
                if (diag) {
                    int kc = k0 + nt * 16 + lr;
                    int qr = q0 + w * 16 + lq * 4 + r;
                    if (kc > qr) v = -1e30f;
                }
                p[nt][r] = v;
            }

        // online softmax per row (row lives in lanes {lq, lq+16, lq+32, lq+48}? no —
        // row owned by 16 lanes with same lq: shuffle over lr bits 1..8)
#pragma unroll
        for (int r = 0; r < 4; r++) {
            float tmax = fmaxf(fmaxf(p[0][r], p[1][r]), fmaxf(p[2][r], p[3][r]));
            tmax = fmaxf(tmax, __shfl_xor(tmax, 1));
            tmax = fmaxf(tmax, __shfl_xor(tmax, 2));
            tmax = fmaxf(tmax, __shfl_xor(tmax, 4));
            tmax = fmaxf(tmax, __shfl_xor(tmax, 8));
            float mnew = fmaxf(m_i[r], tmax);
            float alpha = __expf(m_i[r] - mnew);
            float rsum = 0.f;
#pragma unroll
            for (int nt = 0; nt < 4; nt++) {
                float e = __expf(p[nt][r] - mnew);
                p[nt][r] = e;
                rsum += e;
            }
            rsum += __shfl_xor(rsum, 1);
            rsum += __shfl_xor(rsum, 2);
            rsum += __shfl_xor(rsum, 4);
            rsum += __shfl_xor(rsum, 8);
            l_i[r] = l_i[r] * alpha + rsum;
            m_i[r] = mnew;
#pragma unroll
            for (int dt = 0; dt < 4; dt++) o[dt][r] *= alpha;
        }

        // P (C-layout) -> LDS bf16
#pragma unroll
        for (int nt = 0; nt < 4; nt++)
#pragma unroll
            for (int r = 0; r < 4; r++)
                Ps[w][(lq * 4 + r) * ATT_STRIDE + nt * 16 + lr] = f2bf(p[nt][r]);
        __syncthreads();

        // O += P V
#pragma unroll
        for (int ks = 0; ks < 2; ks++) {
            bf16x8 ap = *(const bf16x8*)&Ps[w][lr * ATT_STRIDE + ks * 32 + lq * 8];
#pragma unroll
            for (int dt = 0; dt < 4; dt++) {
                bf16x8 bv = *(const bf16x8*)&Vs[(dt * 16 + lr) * ATT_STRIDE + ks * 32 + lq * 8];
                o[dt] = mfma16x16x32(ap, bv, o[dt]);
            }
        }
        __syncthreads();
    }

#pragma unroll
    for (int r = 0; r < 4; r++) {
        float inv = 1.0f / l_i[r];
        int qr = q0 + w * 16 + lq * 4 + r;
#pragma unroll
        for (int dt = 0; dt < 4; dt++)
            attn[(size_t)qr * CDIM + h * HD + dt * 16 + lr] = f2bf(o[dt][r] * inv);
    }
}

extern "C" void kernel_launch(void* const* d_in, const int* in_sizes, int n_in,
                              void* d_out, int out_size, void* d_ws, size_t ws_size,
                              hipStream_t stream) {
    const float* x    = (const float*)d_in[0];   // [4096][1024] fp32 (detector-confirmed R5)
    const float* Wqkv = (const float*)d_in[1];   // [1024][3072] fp32
    const float* bqkv = (const float*)d_in[2];   // [3072] fp32
    const float* Wout = (const float*)d_in[3];   // [1024][1024] fp32
    const float* bout = (const float*)d_in[4];   // [1024] fp32
    float* out = (float*)d_out;                  // [4096][1024] fp32  <-- the round-6 fix

    char* ws = (char*)d_ws;
    u16* qkv   = (u16*)(ws);                     // [0, 25165824)
    u16* xb    = (u16*)(ws + 25165824);          // [25165824, 33554432) — aliases attn
    u16* attn  = xb;                             // xb dead after GEMM1
    u16* vt    = (u16*)(ws + 33554432);          // [33554432, 41943040)
    u16* wqkvt = (u16*)(ws + 41943040);          // [41943040, 48234496)
    u16* woutt = (u16*)(ws + 48234496);          // [48234496, 50331648)

    // 1. ingest: x -> bf16; weights -> B^T bf16 (biases stay fp32, used directly)
    k_cast_x<<<dim3(2048), 256, 0, stream>>>(x, xb, 524288);
    k_transpose_cast<<<dim3(96, 32), 256, 0, stream>>>(Wqkv, wqkvt, 1024, 3072);
    k_transpose_cast<<<dim3(32, 32), 256, 0, stream>>>(Wout, woutt, 1024, 1024);
    // 2. qkv = x @ Wqkv + bqkv   (bf16 out)
    k_gemm_bt<u16><<<dim3(24, 32), 256, 0, stream>>>(xb, wqkvt, bqkv, qkv, 4096, 3072, 1024);
    // 3. V^T per head
    k_transpose_v<<<dim3(128, 2, 16), 256, 0, stream>>>(qkv, vt);
    // 4. causal flash attention (MFMA)
    k_attn<<<dim3(64, 16), 256, 0, stream>>>(qkv, vt, attn);
    // 5. out = attn @ Wout + bout   (fp32 out)
    k_gemm_bt<float><<<dim3(8, 32), 256, 0, stream>>>(attn, woutt, bout, out, 4096, 1024, 1024);
}

// Round 7
// 345.507 us; speedup vs baseline: 1.0712x; 1.0712x over previous
//
#include <hip/hip_runtime.h>
#include <hip/hip_bf16.h>

typedef unsigned short u16;
typedef __bf16 bf16x8 __attribute__((ext_vector_type(8)));
typedef float f32x4 __attribute__((ext_vector_type(4)));

#define L_SEQ 4096
#define CDIM  1024
#define NH    16
#define HD    64
#define N_QKV 3072
#define ATT_STRIDE 80   // LDS row stride (halfwords): 160 B, keeps bf16x8 16-B aligned

static __device__ __forceinline__ float bf2f(u16 u) {
    union { float f; unsigned int i; } v; v.i = ((unsigned int)u) << 16; return v.f;
}
static __device__ __forceinline__ u16 f2bf(float f) {
    union { float f; unsigned int i; } v; v.f = f;
    unsigned int u = v.i;
    return (u16)((u + 0x7fffu + ((u >> 16) & 1u)) >> 16);   // RNE
}

static __device__ __forceinline__ f32x4 mfma16x16x32(bf16x8 a, bf16x8 b, f32x4 c) {
    return __builtin_amdgcn_mfma_f32_16x16x32_bf16(a, b, c, 0, 0, 0);
}

// ---------------- x (fp32) -> bf16, 8 elems/thread ----------------
__global__ __launch_bounds__(256) void k_cast_x(const float* __restrict__ src,
                                                u16* __restrict__ dst, int n8) {
    int i = blockIdx.x * 256 + threadIdx.x;
    if (i >= n8) return;
    const float4* s = (const float4*)(src + (size_t)i * 8);
    float4 a = s[0], b = s[1];
    u16 o[8] = { f2bf(a.x), f2bf(a.y), f2bf(a.z), f2bf(a.w),
                 f2bf(b.x), f2bf(b.y), f2bf(b.z), f2bf(b.w) };
    *(uint4*)(dst + (size_t)i * 8) = *(uint4*)o;
}

// ---------------- transpose + cast: src fp32 [R][C] -> dst bf16 [C][R] ----------------
__global__ __launch_bounds__(256) void k_transpose_cast(const float* __restrict__ src,
                                                        u16* __restrict__ dst,
                                                        int R, int C) {
    __shared__ u16 tile[32][33];
    int c0 = blockIdx.x * 32, r0 = blockIdx.y * 32;
    int tx = threadIdx.x & 31, ty = threadIdx.x >> 5;   // 32 x 8
#pragma unroll
    for (int i = 0; i < 32; i += 8)
        tile[ty + i][tx] = f2bf(src[(size_t)(r0 + ty + i) * C + c0 + tx]);
    __syncthreads();
#pragma unroll
    for (int i = 0; i < 32; i += 8)
        dst[(size_t)(c0 + ty + i) * R + r0 + tx] = tile[tx][ty + i];
}

// ---------------- V transpose (bf16): qkv[:, 2C + h*64 + d] -> vt[h*64+d][key] ----------------
__global__ __launch_bounds__(256) void k_transpose_v(const u16* __restrict__ qkv,
                                                     u16* __restrict__ vt) {
    __shared__ u16 tile[32][33];
    int k0 = blockIdx.x * 32, d0 = blockIdx.y * 32, h = blockIdx.z;
    int tx = threadIdx.x & 31, ty = threadIdx.x >> 5;
#pragma unroll
    for (int i = 0; i < 32; i += 8)
        tile[ty + i][tx] = qkv[(size_t)(k0 + ty + i) * N_QKV + 2 * CDIM + h * HD + d0 + tx];
    __syncthreads();
#pragma unroll
    for (int i = 0; i < 32; i += 8)
        vt[(size_t)(h * HD + d0 + ty + i) * L_SEQ + k0 + tx] = tile[tx][ty + i];
}

// ------- GEMM: C[M][N] = A[M][K] @ Bt[N][K]^T + bias[N]; A,Bt bf16; bias fp32;
//         OutT selects epilogue dtype (u16 -> bf16 store, float -> fp32 store) -------
template <typename OutT>
__global__ __launch_bounds__(256) void k_gemm_bt(const u16* __restrict__ A,
                                                 const u16* __restrict__ Bt,
                                                 const float* __restrict__ bias,
                                                 OutT* __restrict__ Cmat,
                                                 int M, int N, int K) {
    __shared__ alignas(16) u16 As[128 * 32];
    __shared__ alignas(16) u16 Bs[128 * 32];
    int t = threadIdx.x;
    int n0 = blockIdx.x * 128, m0 = blockIdx.y * 128;
    int l = t & 63, w = t >> 6;
    int wm = (w >> 1) * 64, wn = (w & 1) * 64;
    int lr = l & 15, lq = l >> 4;

    const f32x4 vzero = {0.f, 0.f, 0.f, 0.f};
    f32x4 acc[4][4];
#pragma unroll
    for (int mi = 0; mi < 4; mi++)
#pragma unroll
        for (int ni = 0; ni < 4; ni++) acc[mi][ni] = vzero;

    int ar = t >> 2;            // 0..63
    int ac = (t & 3) * 8;       // 0,8,16,24
    const u16* Ag = A + (size_t)(m0 + ar) * K + ac;
    const u16* Bg = Bt + (size_t)(n0 + ar) * K + ac;

    for (int k0 = 0; k0 < K; k0 += 32) {
        *(uint4*)&As[ar * 32 + ac]        = *(const uint4*)(Ag + k0);
        *(uint4*)&As[(ar + 64) * 32 + ac] = *(const uint4*)(Ag + (size_t)64 * K + k0);
        *(uint4*)&Bs[ar * 32 + ac]        = *(const uint4*)(Bg + k0);
        *(uint4*)&Bs[(ar + 64) * 32 + ac] = *(const uint4*)(Bg + (size_t)64 * K + k0);
        __syncthreads();

        bf16x8 af[4], bfr[4];
#pragma unroll
        for (int mi = 0; mi < 4; mi++)
            af[mi] = *(const bf16x8*)&As[(wm + mi * 16 + lr) * 32 + lq * 8];
#pragma unroll
        for (int ni = 0; ni < 4; ni++)
            bfr[ni] = *(const bf16x8*)&Bs[(wn + ni * 16 + lr) * 32 + lq * 8];
#pragma unroll
        for (int mi = 0; mi < 4; mi++)
#pragma unroll
            for (int ni = 0; ni < 4; ni++)
                acc[mi][ni] = mfma16x16x32(af[mi], bfr[ni], acc[mi][ni]);
        __syncthreads();
    }

#pragma unroll
    for (int ni = 0; ni < 4; ni++) {
        int col = n0 + wn + ni * 16 + lr;
        float bv = bias[col];
#pragma unroll
        for (int mi = 0; mi < 4; mi++) {
            int row = m0 + wm + mi * 16 + lq * 4;
#pragma unroll
            for (int r = 0; r < 4; r++) {
                float v = acc[mi][ni][r] + bv;
                if constexpr (sizeof(OutT) == 2)
                    Cmat[(size_t)(row + r) * N + col] = f2bf(v);
                else
                    Cmat[(size_t)(row + r) * N + col] = v;
            }
        }
    }
}

// ---------------- causal flash attention, S^T formulation ----------------
// grid: (L/64 q-tiles, NH heads), 256 threads (4 waves; wave w owns 16 Q rows).
// S^T = K·Q^T so each lane's scores all share q = lane&15:
//   - softmax reduction = in-register over 16 vals + shfl_xor(16,32)  (4 shfl vs 32)
//   - P^T C-layout (key = lq*4+r) feeds PV's B-operand directly from registers:
//     two 16-key tiles packed into one K=32 fragment; A-operand (V^T) reads the
//     same (quad,j)->key mapping via two ds_read_b64. No P LDS roundtrip.
// O^T accumulates in C-layout (col=q=lr, row=d=lq*4+r); epilogue packs 8-B stores.
__global__ __launch_bounds__(256) void k_attn(const u16* __restrict__ qkv,
                                              const u16* __restrict__ vt,
                                              u16* __restrict__ attn) {
    __shared__ alignas(16) u16 Ks[64 * ATT_STRIDE];   // [key][d]
    __shared__ alignas(16) u16 Vs[64 * ATT_STRIDE];   // [d][key]  (V^T)

    int t = threadIdx.x;
    int l = t & 63, w = t >> 6;
    int q0 = blockIdx.x * 64, h = blockIdx.y;
    int lr = l & 15, lq = l >> 4;

    // Q as B-operand frags: B[k=lq*8+j][n=lr], pre-scaled by 1/sqrt(D)=0.125 (exact)
    bf16x8 bq[2];
    {
        const u16* Qg = qkv + (size_t)(q0 + w * 16 + lr) * N_QKV + h * HD + lq * 8;
        union { uint4 u; u16 hh[8]; } q0u, q1u;
        q0u.u = *(const uint4*)(Qg);
        q1u.u = *(const uint4*)(Qg + 32);
        union { bf16x8 v; u16 hh[8]; } f0, f1;
#pragma unroll
        for (int j = 0; j < 8; j++) {
            f0.hh[j] = f2bf(bf2f(q0u.hh[j]) * 0.125f);
            f1.hh[j] = f2bf(bf2f(q1u.hh[j]) * 0.125f);
        }
        bq[0] = f0.v; bq[1] = f1.v;
    }

    const f32x4 vzero = {0.f, 0.f, 0.f, 0.f};
    f32x4 o[4];                       // O^T[d][q]: col=q=lr, row(dt)=lq*4+r
#pragma unroll
    for (int dt = 0; dt < 4; dt++) o[dt] = vzero;
    float m_i = -1e30f, l_i = 0.f;    // per-lane q = q0 + w*16 + lr

    int row8 = t >> 3;          // 0..31
    int ch = (t & 7) * 8;       // 0..56
    int nkv = q0 / 64 + 1;
    int qidx = w * 16 + lr;     // q within block

    for (int it = 0; it < nkv; ++it) {
        int k0 = it * 64;
        const u16* Kg = qkv + (size_t)(k0 + row8) * N_QKV + CDIM + h * HD + ch;
        *(uint4*)&Ks[row8 * ATT_STRIDE + ch]        = *(const uint4*)Kg;
        *(uint4*)&Ks[(row8 + 32) * ATT_STRIDE + ch] = *(const uint4*)(Kg + (size_t)32 * N_QKV);
        const u16* Vg = vt + (size_t)(h * HD + row8) * L_SEQ + k0 + ch;
        *(uint4*)&Vs[row8 * ATT_STRIDE + ch]        = *(const uint4*)Vg;
        *(uint4*)&Vs[(row8 + 32) * ATT_STRIDE + ch] = *(const uint4*)(Vg + (size_t)32 * L_SEQ);
        __syncthreads();

        // S^T = K Q^T: A = K-tile rows (m=key), B = Q frags (n=q).
        // C-layout: row = key = nt*16 + lq*4 + r, col = q = lr.
        f32x4 s[4];
#pragma unroll
        for (int nt = 0; nt < 4; nt++) s[nt] = vzero;
#pragma unroll
        for (int ks = 0; ks < 2; ks++)
#pragma unroll
            for (int nt = 0; nt < 4; nt++) {
                bf16x8 ak = *(const bf16x8*)&Ks[(nt * 16 + lr) * ATT_STRIDE + ks * 32 + lq * 8];
                s[nt] = mfma16x16x32(ak, bq[ks], s[nt]);
            }

        // mask (diag tile only) + lane-local max over this lane's 16 keys
        bool diag = (k0 == q0);
        float tmax = -1e30f;
#pragma unroll
        for (int nt = 0; nt < 4; nt++)
#pragma unroll
            for (int r = 0; r < 4; r++) {
                float v = s[nt][r];
                if (diag && (nt * 16 + lq * 4 + r > qidx)) v = -1e30f;
                s[nt][r] = v;
                tmax = fmaxf(tmax, v);
            }
        tmax = fmaxf(tmax, __shfl_xor(tmax, 16));
        tmax = fmaxf(tmax, __shfl_xor(tmax, 32));

        float mnew = fmaxf(m_i, tmax);
        float alpha = __expf(m_i - mnew);
        float rsum = 0.f;
#pragma unroll
        for (int nt = 0; nt < 4; nt++)
#pragma unroll
            for (int r = 0; r < 4; r++) {
                float e = __expf(s[nt][r] - mnew);
                s[nt][r] = e;
                rsum += e;
            }
        rsum += __shfl_xor(rsum, 16);
        rsum += __shfl_xor(rsum, 32);
        l_i = l_i * alpha + rsum;
        m_i = mnew;
#pragma unroll
        for (int dt = 0; dt < 4; dt++)
#pragma unroll
            for (int r = 0; r < 4; r++) o[dt][r] *= alpha;

        // PV: O^T[d][q] += V^T[d][key] * P^T[key][q], two 16-key tiles per K=32 MFMA.
        // slot (quad=lq, j): key = a*32 + lq*4 + j   (j<4, tile 2a)
        //                    key = a*32 + 16 + lq*4 + (j-4) (j>=4, tile 2a+1)
#pragma unroll
        for (int a = 0; a < 2; a++) {
            union { bf16x8 v; u16 hh[8]; } bp;
#pragma unroll
            for (int r = 0; r < 4; r++) {
                bp.hh[r]     = f2bf(s[2 * a][r]);
                bp.hh[r + 4] = f2bf(s[2 * a + 1][r]);
            }
#pragma unroll
            for (int dt = 0; dt < 4; dt++) {
                union { bf16x8 v; uint2 u2[2]; } av;
                const u16* vrow = &Vs[(dt * 16 + lr) * ATT_STRIDE + a * 32 + lq * 4];
                av.u2[0] = *(const uint2*)(vrow);
                av.u2[1] = *(const uint2*)(vrow + 16);
                o[dt] = mfma16x16x32(av.v, bp.v, o[dt]);
            }
        }
        __syncthreads();
    }

    // epilogue: attn[q][h*64 + d], d = dt*16 + lq*4 + r -> packed 8-B stores
    float inv = 1.0f / l_i;
    int qg = q0 + qidx;
#pragma unroll
    for (int dt = 0; dt < 4; dt++) {
        union { u16 hh[4]; uint2 u2; } eo;
#pragma unroll
        for (int r = 0; r < 4; r++) eo.hh[r] = f2bf(o[dt][r] * inv);
        *(uint2*)&attn[(size_t)qg * CDIM + h * HD + dt * 16 + lq * 4] = eo.u2;
    }
}

extern "C" void kernel_launch(void* const* d_in, const int* in_sizes, int n_in,
                              void* d_out, int out_size, void* d_ws, size_t ws_size,
                              hipStream_t stream) {
    const float* x    = (const float*)d_in[0];   // [4096][1024] fp32
    const float* Wqkv = (const float*)d_in[1];   // [1024][3072] fp32
    const float* bqkv = (const float*)d_in[2];   // [3072] fp32
    const float* Wout = (const float*)d_in[3];   // [1024][1024] fp32
    const float* bout = (const float*)d_in[4];   // [1024] fp32
    float* out = (float*)d_out;                  // [4096][1024] fp32

    char* ws = (char*)d_ws;
    u16* qkv   = (u16*)(ws);                     // [0, 25165824)
    u16* xb    = (u16*)(ws + 25165824);          // [25165824, 33554432) — aliases attn
    u16* attn  = xb;                             // xb dead after GEMM1
    u16* vt    = (u16*)(ws + 33554432);          // [33554432, 41943040)
    u16* wqkvt = (u16*)(ws + 41943040);          // [41943040, 48234496)
    u16* woutt = (u16*)(ws + 48234496);          // [48234496, 50331648)

    // 1. ingest: x -> bf16; weights -> B^T bf16 (biases stay fp32)
    k_cast_x<<<dim3(2048), 256, 0, stream>>>(x, xb, 524288);
    k_transpose_cast<<<dim3(96, 32), 256, 0, stream>>>(Wqkv, wqkvt, 1024, 3072);
    k_transpose_cast<<<dim3(32, 32), 256, 0, stream>>>(Wout, woutt, 1024, 1024);
    // 2. qkv = x @ Wqkv + bqkv   (bf16 out)
    k_gemm_bt<u16><<<dim3(24, 32), 256, 0, stream>>>(xb, wqkvt, bqkv, qkv, 4096, 3072, 1024);
    // 3. V^T per head
    k_transpose_v<<<dim3(128, 2, 16), 256, 0, stream>>>(qkv, vt);
    // 4. causal flash attention (S^T formulation)
    k_attn<<<dim3(64, 16), 256, 0, stream>>>(qkv, vt, attn);
    // 5. out = attn @ Wout + bout   (fp32 out)
    k_gemm_bt<float><<<dim3(8, 32), 256, 0, stream>>>(attn, woutt, bout, out, 4096, 1024, 1024);
}

// Round 8
// 307.169 us; speedup vs baseline: 1.2049x; 1.1248x over previous
//
#include <hip/hip_runtime.h>
#include <hip/hip_bf16.h>

typedef unsigned short u16;
typedef __bf16 bf16x8 __attribute__((ext_vector_type(8)));
typedef float f32x4 __attribute__((ext_vector_type(4)));

#define L_SEQ 4096
#define CDIM  1024
#define NH    16
#define HD    64
#define N_QKV 3072
// LDS row stride (halfwords). 88 hw = 176 B: 16-B aligned rows AND 44 dw = 12 mod 32
// -> within-octet banks 12*lr mod 32 all distinct (conflict-free b128 phases).
#define ATT_STRIDE 88

static __device__ __forceinline__ float bf2f(u16 u) {
    union { float f; unsigned int i; } v; v.i = ((unsigned int)u) << 16; return v.f;
}
static __device__ __forceinline__ u16 f2bf(float f) {
    union { float f; unsigned int i; } v; v.f = f;
    unsigned int u = v.i;
    return (u16)((u + 0x7fffu + ((u >> 16) & 1u)) >> 16);   // RNE
}

static __device__ __forceinline__ f32x4 mfma16x16x32(bf16x8 a, bf16x8 b, f32x4 c) {
    return __builtin_amdgcn_mfma_f32_16x16x32_bf16(a, b, c, 0, 0, 0);
}

// ---------------- x (fp32) -> bf16, 8 elems/thread ----------------
__global__ __launch_bounds__(256) void k_cast_x(const float* __restrict__ src,
                                                u16* __restrict__ dst, int n8) {
    int i = blockIdx.x * 256 + threadIdx.x;
    if (i >= n8) return;
    const float4* s = (const float4*)(src + (size_t)i * 8);
    float4 a = s[0], b = s[1];
    u16 o[8] = { f2bf(a.x), f2bf(a.y), f2bf(a.z), f2bf(a.w),
                 f2bf(b.x), f2bf(b.y), f2bf(b.z), f2bf(b.w) };
    *(uint4*)(dst + (size_t)i * 8) = *(uint4*)o;
}

// ---------------- transpose + cast: src fp32 [R][C] -> dst bf16 [C][R] ----------------
__global__ __launch_bounds__(256) void k_transpose_cast(const float* __restrict__ src,
                                                        u16* __restrict__ dst,
                                                        int R, int C) {
    __shared__ u16 tile[32][33];
    int c0 = blockIdx.x * 32, r0 = blockIdx.y * 32;
    int tx = threadIdx.x & 31, ty = threadIdx.x >> 5;   // 32 x 8
#pragma unroll
    for (int i = 0; i < 32; i += 8)
        tile[ty + i][tx] = f2bf(src[(size_t)(r0 + ty + i) * C + c0 + tx]);
    __syncthreads();
#pragma unroll
    for (int i = 0; i < 32; i += 8)
        dst[(size_t)(c0 + ty + i) * R + r0 + tx] = tile[tx][ty + i];
}

// ---------------- V transpose (bf16): qkv[:, 2C + h*64 + d] -> vt[h*64+d][key] ----------------
__global__ __launch_bounds__(256) void k_transpose_v(const u16* __restrict__ qkv,
                                                     u16* __restrict__ vt) {
    __shared__ u16 tile[32][33];
    int k0 = blockIdx.x * 32, d0 = blockIdx.y * 32, h = blockIdx.z;
    int tx = threadIdx.x & 31, ty = threadIdx.x >> 5;
#pragma unroll
    for (int i = 0; i < 32; i += 8)
        tile[ty + i][tx] = qkv[(size_t)(k0 + ty + i) * N_QKV + 2 * CDIM + h * HD + d0 + tx];
    __syncthreads();
#pragma unroll
    for (int i = 0; i < 32; i += 8)
        vt[(size_t)(h * HD + d0 + ty + i) * L_SEQ + k0 + tx] = tile[tx][ty + i];
}

// ------- GEMM: C[M][N] = A[M][K] @ Bt[N][K]^T + bias[N]; A,Bt bf16; bias fp32;
//         OutT selects epilogue dtype (u16 -> bf16 store, float -> fp32 store) -------
template <typename OutT>
__global__ __launch_bounds__(256) void k_gemm_bt(const u16* __restrict__ A,
                                                 const u16* __restrict__ Bt,
                                                 const float* __restrict__ bias,
                                                 OutT* __restrict__ Cmat,
                                                 int M, int N, int K) {
    __shared__ alignas(16) u16 As[128 * 32];
    __shared__ alignas(16) u16 Bs[128 * 32];
    int t = threadIdx.x;
    int n0 = blockIdx.x * 128, m0 = blockIdx.y * 128;
    int l = t & 63, w = t >> 6;
    int wm = (w >> 1) * 64, wn = (w & 1) * 64;
    int lr = l & 15, lq = l >> 4;

    const f32x4 vzero = {0.f, 0.f, 0.f, 0.f};
    f32x4 acc[4][4];
#pragma unroll
    for (int mi = 0; mi < 4; mi++)
#pragma unroll
        for (int ni = 0; ni < 4; ni++) acc[mi][ni] = vzero;

    int ar = t >> 2;            // 0..63
    int ac = (t & 3) * 8;       // 0,8,16,24
    const u16* Ag = A + (size_t)(m0 + ar) * K + ac;
    const u16* Bg = Bt + (size_t)(n0 + ar) * K + ac;

    for (int k0 = 0; k0 < K; k0 += 32) {
        *(uint4*)&As[ar * 32 + ac]        = *(const uint4*)(Ag + k0);
        *(uint4*)&As[(ar + 64) * 32 + ac] = *(const uint4*)(Ag + (size_t)64 * K + k0);
        *(uint4*)&Bs[ar * 32 + ac]        = *(const uint4*)(Bg + k0);
        *(uint4*)&Bs[(ar + 64) * 32 + ac] = *(const uint4*)(Bg + (size_t)64 * K + k0);
        __syncthreads();

        bf16x8 af[4], bfr[4];
#pragma unroll
        for (int mi = 0; mi < 4; mi++)
            af[mi] = *(const bf16x8*)&As[(wm + mi * 16 + lr) * 32 + lq * 8];
#pragma unroll
        for (int ni = 0; ni < 4; ni++)
            bfr[ni] = *(const bf16x8*)&Bs[(wn + ni * 16 + lr) * 32 + lq * 8];
#pragma unroll
        for (int mi = 0; mi < 4; mi++)
#pragma unroll
            for (int ni = 0; ni < 4; ni++)
                acc[mi][ni] = mfma16x16x32(af[mi], bfr[ni], acc[mi][ni]);
        __syncthreads();
    }

#pragma unroll
    for (int ni = 0; ni < 4; ni++) {
        int col = n0 + wn + ni * 16 + lr;
        float bv = bias[col];
#pragma unroll
        for (int mi = 0; mi < 4; mi++) {
            int row = m0 + wm + mi * 16 + lq * 4;
#pragma unroll
            for (int r = 0; r < 4; r++) {
                float v = acc[mi][ni][r] + bv;
                if constexpr (sizeof(OutT) == 2)
                    Cmat[(size_t)(row + r) * N + col] = f2bf(v);
                else
                    Cmat[(size_t)(row + r) * N + col] = v;
            }
        }
    }
}

// ---------------- causal flash attention, S^T formulation + paired q-tiles ----------------
// grid: (32 pairs, NH heads), 256 threads. Block handles q-tiles {px, 63-px} sequentially:
// (px+1) + (64-px) = 65 KV-iters for every block -> perfectly uniform CU load under any
// dispatch policy (fixes the x = cu%64 round-robin straggler: worst-CU 256 -> 130 iters).
__global__ __launch_bounds__(256) void k_attn(const u16* __restrict__ qkv,
                                              const u16* __restrict__ vt,
                                              u16* __restrict__ attn) {
    __shared__ alignas(16) u16 Ks[64 * ATT_STRIDE];   // [key][d]
    __shared__ alignas(16) u16 Vs[64 * ATT_STRIDE];   // [d][key]  (V^T)

    int t = threadIdx.x;
    int l = t & 63, w = t >> 6;
    int h = blockIdx.y;
    int lr = l & 15, lq = l >> 4;
    int row8 = t >> 3;          // 0..31
    int ch = (t & 7) * 8;       // 0..56
    int qloc = w * 16 + lr;     // q within tile, this lane

    const f32x4 vzero = {0.f, 0.f, 0.f, 0.f};

#pragma unroll
    for (int phase = 0; phase < 2; phase++) {
        int tile = phase ? (63 - blockIdx.x) : blockIdx.x;
        int q0 = tile * 64;
        int nkv = tile + 1;
        int qidx = qloc;

        // Q as B-operand frags: B[k=lq*8+j][n=lr], pre-scaled by 1/8 (exact)
        bf16x8 bq[2];
        {
            const u16* Qg = qkv + (size_t)(q0 + qloc) * N_QKV + h * HD + lq * 8;
            union { uint4 u; u16 hh[8]; } q0u, q1u;
            q0u.u = *(const uint4*)(Qg);
            q1u.u = *(const uint4*)(Qg + 32);
            union { bf16x8 v; u16 hh[8]; } f0, f1;
#pragma unroll
            for (int j = 0; j < 8; j++) {
                f0.hh[j] = f2bf(bf2f(q0u.hh[j]) * 0.125f);
                f1.hh[j] = f2bf(bf2f(q1u.hh[j]) * 0.125f);
            }
            bq[0] = f0.v; bq[1] = f1.v;
        }

        f32x4 o[4];                       // O^T[d][q]: col=q=lr, row(dt)=lq*4+r
#pragma unroll
        for (int dt = 0; dt < 4; dt++) o[dt] = vzero;
        float m_i = -1e30f, l_i = 0.f;

        for (int it = 0; it < nkv; ++it) {
            int k0 = it * 64;
            const u16* Kg = qkv + (size_t)(k0 + row8) * N_QKV + CDIM + h * HD + ch;
            *(uint4*)&Ks[row8 * ATT_STRIDE + ch]        = *(const uint4*)Kg;
            *(uint4*)&Ks[(row8 + 32) * ATT_STRIDE + ch] = *(const uint4*)(Kg + (size_t)32 * N_QKV);
            const u16* Vg = vt + (size_t)(h * HD + row8) * L_SEQ + k0 + ch;
            *(uint4*)&Vs[row8 * ATT_STRIDE + ch]        = *(const uint4*)Vg;
            *(uint4*)&Vs[(row8 + 32) * ATT_STRIDE + ch] = *(const uint4*)(Vg + (size_t)32 * L_SEQ);
            __syncthreads();

            // S^T = K Q^T: C-layout row = key = nt*16 + lq*4 + r, col = q = lr.
            f32x4 s[4];
#pragma unroll
            for (int nt = 0; nt < 4; nt++) s[nt] = vzero;
#pragma unroll
            for (int ks = 0; ks < 2; ks++)
#pragma unroll
                for (int nt = 0; nt < 4; nt++) {
                    bf16x8 ak = *(const bf16x8*)&Ks[(nt * 16 + lr) * ATT_STRIDE + ks * 32 + lq * 8];
                    s[nt] = mfma16x16x32(ak, bq[ks], s[nt]);
                }

            bool diag = (k0 == q0);
            float tmax = -1e30f;
#pragma unroll
            for (int nt = 0; nt < 4; nt++)
#pragma unroll
                for (int r = 0; r < 4; r++) {
                    float v = s[nt][r];
                    if (diag && (nt * 16 + lq * 4 + r > qidx)) v = -1e30f;
                    s[nt][r] = v;
                    tmax = fmaxf(tmax, v);
                }
            tmax = fmaxf(tmax, __shfl_xor(tmax, 16));
            tmax = fmaxf(tmax, __shfl_xor(tmax, 32));

            float mnew = fmaxf(m_i, tmax);
            float alpha = __expf(m_i - mnew);
            float rsum = 0.f;
#pragma unroll
            for (int nt = 0; nt < 4; nt++)
#pragma unroll
                for (int r = 0; r < 4; r++) {
                    float e = __expf(s[nt][r] - mnew);
                    s[nt][r] = e;
                    rsum += e;
                }
            rsum += __shfl_xor(rsum, 16);
            rsum += __shfl_xor(rsum, 32);
            l_i = l_i * alpha + rsum;
            m_i = mnew;
#pragma unroll
            for (int dt = 0; dt < 4; dt++)
#pragma unroll
                for (int r = 0; r < 4; r++) o[dt][r] *= alpha;

            // PV: O^T[d][q] += V^T[d][key] * P^T[key][q]; two 16-key tiles per K=32 MFMA.
#pragma unroll
            for (int a = 0; a < 2; a++) {
                union { bf16x8 v; u16 hh[8]; } bp;
#pragma unroll
                for (int r = 0; r < 4; r++) {
                    bp.hh[r]     = f2bf(s[2 * a][r]);
                    bp.hh[r + 4] = f2bf(s[2 * a + 1][r]);
                }
#pragma unroll
                for (int dt = 0; dt < 4; dt++) {
                    union { bf16x8 v; uint2 u2[2]; } av;
                    const u16* vrow = &Vs[(dt * 16 + lr) * ATT_STRIDE + a * 32 + lq * 4];
                    av.u2[0] = *(const uint2*)(vrow);
                    av.u2[1] = *(const uint2*)(vrow + 16);
                    o[dt] = mfma16x16x32(av.v, bp.v, o[dt]);
                }
            }
            __syncthreads();
        }

        // epilogue: attn[q][h*64 + d], d = dt*16 + lq*4 + r -> packed 8-B stores
        float inv = 1.0f / l_i;
        int qg = q0 + qidx;
#pragma unroll
        for (int dt = 0; dt < 4; dt++) {
            union { u16 hh[4]; uint2 u2; } eo;
#pragma unroll
            for (int r = 0; r < 4; r++) eo.hh[r] = f2bf(o[dt][r] * inv);
            *(uint2*)&attn[(size_t)qg * CDIM + h * HD + dt * 16 + lq * 4] = eo.u2;
        }
    }
}

extern "C" void kernel_launch(void* const* d_in, const int* in_sizes, int n_in,
                              void* d_out, int out_size, void* d_ws, size_t ws_size,
                              hipStream_t stream) {
    const float* x    = (const float*)d_in[0];   // [4096][1024] fp32
    const float* Wqkv = (const float*)d_in[1];   // [1024][3072] fp32
    const float* bqkv = (const float*)d_in[2];   // [3072] fp32
    const float* Wout = (const float*)d_in[3];   // [1024][1024] fp32
    const float* bout = (const float*)d_in[4];   // [1024] fp32
    float* out = (float*)d_out;                  // [4096][1024] fp32

    char* ws = (char*)d_ws;
    u16* qkv   = (u16*)(ws);                     // [0, 25165824)
    u16* xb    = (u16*)(ws + 25165824);          // [25165824, 33554432) — aliases attn
    u16* attn  = xb;                             // xb dead after GEMM1
    u16* vt    = (u16*)(ws + 33554432);          // [33554432, 41943040)
    u16* wqkvt = (u16*)(ws + 41943040);          // [41943040, 48234496)
    u16* woutt = (u16*)(ws + 48234496);          // [48234496, 50331648)

    // 1. ingest: x -> bf16; weights -> B^T bf16 (biases stay fp32)
    k_cast_x<<<dim3(2048), 256, 0, stream>>>(x, xb, 524288);
    k_transpose_cast<<<dim3(96, 32), 256, 0, stream>>>(Wqkv, wqkvt, 1024, 3072);
    k_transpose_cast<<<dim3(32, 32), 256, 0, stream>>>(Wout, woutt, 1024, 1024);
    // 2. qkv = x @ Wqkv + bqkv   (bf16 out)
    k_gemm_bt<u16><<<dim3(24, 32), 256, 0, stream>>>(xb, wqkvt, bqkv, qkv, 4096, 3072, 1024);
    // 3. V^T per head
    k_transpose_v<<<dim3(128, 2, 16), 256, 0, stream>>>(qkv, vt);
    // 4. causal flash attention (S^T formulation, paired q-tiles for load balance)
    k_attn<<<dim3(32, 16), 256, 0, stream>>>(qkv, vt, attn);
    // 5. out = attn @ Wout + bout   (fp32 out)
    k_gemm_bt<float><<<dim3(8, 32), 256, 0, stream>>>(attn, woutt, bout, out, 4096, 1024, 1024);
}

// Round 9
// 246.558 us; speedup vs baseline: 1.5011x; 1.2458x over previous
//
#include <hip/hip_runtime.h>
#include <hip/hip_bf16.h>

typedef unsigned short u16;
typedef __bf16 bf16x8 __attribute__((ext_vector_type(8)));
typedef float f32x4 __attribute__((ext_vector_type(4)));

#define L_SEQ 4096
#define CDIM  1024
#define NH    16
#define HD    64
#define N_QKV 3072
// LDS row stride (halfwords). 88 hw = 176 B: 16-B aligned rows AND 44 dw = 12 mod 32
// -> within-octet banks 12*lr mod 32 all distinct (conflict-free b128 phases).
#define ATT_STRIDE 88

static __device__ __forceinline__ float bf2f(u16 u) {
    union { float f; unsigned int i; } v; v.i = ((unsigned int)u) << 16; return v.f;
}
static __device__ __forceinline__ u16 f2bf(float f) {
    union { float f; unsigned int i; } v; v.f = f;
    unsigned int u = v.i;
    return (u16)((u + 0x7fffu + ((u >> 16) & 1u)) >> 16);   // RNE
}

static __device__ __forceinline__ f32x4 mfma16x16x32(bf16x8 a, bf16x8 b, f32x4 c) {
    return __builtin_amdgcn_mfma_f32_16x16x32_bf16(a, b, c, 0, 0, 0);
}

// async global->LDS, 16 B per lane (emits global_load_lds_dwordx4; m97 pattern).
// LDS dest must be wave-uniform base + lane*16 — our callers satisfy this.
typedef const __attribute__((address_space(1))) unsigned int* gas_u32;
typedef __attribute__((address_space(3))) unsigned int* las_u32;
static __device__ __forceinline__ void gload_lds16(const u16* g, u16* l) {
    __builtin_amdgcn_global_load_lds((gas_u32)g, (las_u32)l, 16, 0, 0);
}

// ---------------- x (fp32) -> bf16, 8 elems/thread ----------------
__global__ __launch_bounds__(256) void k_cast_x(const float* __restrict__ src,
                                                u16* __restrict__ dst, int n8) {
    int i = blockIdx.x * 256 + threadIdx.x;
    if (i >= n8) return;
    const float4* s = (const float4*)(src + (size_t)i * 8);
    float4 a = s[0], b = s[1];
    u16 o[8] = { f2bf(a.x), f2bf(a.y), f2bf(a.z), f2bf(a.w),
                 f2bf(b.x), f2bf(b.y), f2bf(b.z), f2bf(b.w) };
    *(uint4*)(dst + (size_t)i * 8) = *(uint4*)o;
}

// ---------------- transpose + cast: src fp32 [R][C] -> dst bf16 [C][R] ----------------
__global__ __launch_bounds__(256) void k_transpose_cast(const float* __restrict__ src,
                                                        u16* __restrict__ dst,
                                                        int R, int C) {
    __shared__ u16 tile[32][33];
    int c0 = blockIdx.x * 32, r0 = blockIdx.y * 32;
    int tx = threadIdx.x & 31, ty = threadIdx.x >> 5;   // 32 x 8
#pragma unroll
    for (int i = 0; i < 32; i += 8)
        tile[ty + i][tx] = f2bf(src[(size_t)(r0 + ty + i) * C + c0 + tx]);
    __syncthreads();
#pragma unroll
    for (int i = 0; i < 32; i += 8)
        dst[(size_t)(c0 + ty + i) * R + r0 + tx] = tile[tx][ty + i];
}

// ---------------- V transpose (bf16): qkv[:, 2C + h*64 + d] -> vt[h*64+d][key] ----------------
__global__ __launch_bounds__(256) void k_transpose_v(const u16* __restrict__ qkv,
                                                     u16* __restrict__ vt) {
    __shared__ u16 tile[32][33];
    int k0 = blockIdx.x * 32, d0 = blockIdx.y * 32, h = blockIdx.z;
    int tx = threadIdx.x & 31, ty = threadIdx.x >> 5;
#pragma unroll
    for (int i = 0; i < 32; i += 8)
        tile[ty + i][tx] = qkv[(size_t)(k0 + ty + i) * N_QKV + 2 * CDIM + h * HD + d0 + tx];
    __syncthreads();
#pragma unroll
    for (int i = 0; i < 32; i += 8)
        vt[(size_t)(h * HD + d0 + ty + i) * L_SEQ + k0 + tx] = tile[tx][ty + i];
}

// ------- GEMM: C[M][N] = A[M][K] @ Bt[N][K]^T + bias[N]; A,Bt bf16; bias fp32;
//         staging via global_load_lds width=16 (m97); OutT selects epilogue dtype -------
template <typename OutT>
__global__ __launch_bounds__(256) void k_gemm_bt(const u16* __restrict__ A,
                                                 const u16* __restrict__ Bt,
                                                 const float* __restrict__ bias,
                                                 OutT* __restrict__ Cmat,
                                                 int M, int N, int K) {
    __shared__ alignas(16) u16 As[128 * 32];
    __shared__ alignas(16) u16 Bs[128 * 32];
    int t = threadIdx.x;
    int n0 = blockIdx.x * 128, m0 = blockIdx.y * 128;
    int l = t & 63, w = t >> 6;
    int wm = (w >> 1) * 64, wn = (w & 1) * 64;
    int lr = l & 15, lq = l >> 4;

    const f32x4 vzero = {0.f, 0.f, 0.f, 0.f};
    f32x4 acc[4][4];
#pragma unroll
    for (int mi = 0; mi < 4; mi++)
#pragma unroll
        for (int ni = 0; ni < 4; ni++) acc[mi][ni] = vzero;

    int ar = t >> 2;            // 0..63
    int ac = (t & 3) * 8;       // 0,8,16,24  -> LDS hw index ar*32+ac == t*8 (base+lane*16B)
    const u16* Ag = A + (size_t)(m0 + ar) * K + ac;
    const u16* Bg = Bt + (size_t)(n0 + ar) * K + ac;
    u16* AsD0 = &As[t * 8];
    u16* AsD1 = &As[t * 8 + 64 * 32];
    u16* BsD0 = &Bs[t * 8];
    u16* BsD1 = &Bs[t * 8 + 64 * 32];

    for (int k0 = 0; k0 < K; k0 += 32) {
        gload_lds16(Ag + k0,                     AsD0);
        gload_lds16(Ag + (size_t)64 * K + k0,    AsD1);
        gload_lds16(Bg + k0,                     BsD0);
        gload_lds16(Bg + (size_t)64 * K + k0,    BsD1);
        __syncthreads();

        bf16x8 af[4], bfr[4];
#pragma unroll
        for (int mi = 0; mi < 4; mi++)
            af[mi] = *(const bf16x8*)&As[(wm + mi * 16 + lr) * 32 + lq * 8];
#pragma unroll
        for (int ni = 0; ni < 4; ni++)
            bfr[ni] = *(const bf16x8*)&Bs[(wn + ni * 16 + lr) * 32 + lq * 8];
#pragma unroll
        for (int mi = 0; mi < 4; mi++)
#pragma unroll
            for (int ni = 0; ni < 4; ni++)
                acc[mi][ni] = mfma16x16x32(af[mi], bfr[ni], acc[mi][ni]);
        __syncthreads();
    }

#pragma unroll
    for (int ni = 0; ni < 4; ni++) {
        int col = n0 + wn + ni * 16 + lr;
        float bv = bias[col];
#pragma unroll
        for (int mi = 0; mi < 4; mi++) {
            int row = m0 + wm + mi * 16 + lq * 4;
#pragma unroll
            for (int r = 0; r < 4; r++) {
                float v = acc[mi][ni][r] + bv;
                if constexpr (sizeof(OutT) == 2)
                    Cmat[(size_t)(row + r) * N + col] = f2bf(v);
                else
                    Cmat[(size_t)(row + r) * N + col] = v;
            }
        }
    }
}

// ---------------- causal flash attention: S^T formulation + paired q-tiles +
//                  register-prefetch software pipeline ----------------
// grid: (32 pairs, NH heads), 256 threads. Block handles q-tiles {px, 63-px} sequentially
// (65 KV-iters/block, uniform). Per iter: KV tile it+1 is prefetched into registers
// right after the first barrier so HBM latency overlaps the MFMA/softmax compute.
__global__ __launch_bounds__(256) void k_attn(const u16* __restrict__ qkv,
                                              const u16* __restrict__ vt,
                                              u16* __restrict__ attn) {
    __shared__ alignas(16) u16 Ks[64 * ATT_STRIDE];   // [key][d]
    __shared__ alignas(16) u16 Vs[64 * ATT_STRIDE];   // [d][key]  (V^T)

    int t = threadIdx.x;
    int l = t & 63, w = t >> 6;
    int h = blockIdx.y;
    int lr = l & 15, lq = l >> 4;
    int row8 = t >> 3;          // 0..31
    int ch = (t & 7) * 8;       // 0..56
    int qloc = w * 16 + lr;     // q within tile, this lane

    const f32x4 vzero = {0.f, 0.f, 0.f, 0.f};
    const u16* Kbase = qkv + (size_t)row8 * N_QKV + CDIM + h * HD + ch;   // + k0*N_QKV
    const u16* Vbase = vt + (size_t)(h * HD + row8) * L_SEQ + ch;         // + k0

#pragma unroll
    for (int phase = 0; phase < 2; phase++) {
        int tile = phase ? (63 - blockIdx.x) : blockIdx.x;
        int q0 = tile * 64;
        int nkv = tile + 1;

        // Q as B-operand frags: B[k=lq*8+j][n=lr], pre-scaled by 1/8 (exact)
        bf16x8 bq[2];
        {
            const u16* Qg = qkv + (size_t)(q0 + qloc) * N_QKV + h * HD + lq * 8;
            union { uint4 u; u16 hh[8]; } q0u, q1u;
            q0u.u = *(const uint4*)(Qg);
            q1u.u = *(const uint4*)(Qg + 32);
            union { bf16x8 v; u16 hh[8]; } f0, f1;
#pragma unroll
            for (int j = 0; j < 8; j++) {
                f0.hh[j] = f2bf(bf2f(q0u.hh[j]) * 0.125f);
                f1.hh[j] = f2bf(bf2f(q1u.hh[j]) * 0.125f);
            }
            bq[0] = f0.v; bq[1] = f1.v;
        }

        f32x4 o[4];                       // O^T[d][q]: col=q=lr, row(dt)=lq*4+r
#pragma unroll
        for (int dt = 0; dt < 4; dt++) o[dt] = vzero;
        float m_i = -1e30f, l_i = 0.f;

        // preload KV tile 0 of this phase into registers
        uint4 rk0, rk1, rv0, rv1;
        {
            const u16* Kg = Kbase;
            rk0 = *(const uint4*)Kg;
            rk1 = *(const uint4*)(Kg + (size_t)32 * N_QKV);
            const u16* Vg = Vbase;
            rv0 = *(const uint4*)Vg;
            rv1 = *(const uint4*)(Vg + (size_t)32 * L_SEQ);
        }

        for (int it = 0; it < nkv; ++it) {
            // stage current KV regs -> LDS
            *(uint4*)&Ks[row8 * ATT_STRIDE + ch]        = rk0;
            *(uint4*)&Ks[(row8 + 32) * ATT_STRIDE + ch] = rk1;
            *(uint4*)&Vs[row8 * ATT_STRIDE + ch]        = rv0;
            *(uint4*)&Vs[(row8 + 32) * ATT_STRIDE + ch] = rv1;
            __syncthreads();

            // prefetch next KV tile (overlaps with compute below)
            if (it + 1 < nkv) {
                int k1 = (it + 1) * 64;
                const u16* Kg = Kbase + (size_t)k1 * N_QKV;
                rk0 = *(const uint4*)Kg;
                rk1 = *(const uint4*)(Kg + (size_t)32 * N_QKV);
                const u16* Vg = Vbase + k1;
                rv0 = *(const uint4*)Vg;
                rv1 = *(const uint4*)(Vg + (size_t)32 * L_SEQ);
            }

            // S^T = K Q^T: C-layout row = key = nt*16 + lq*4 + r, col = q = lr.
            f32x4 s[4];
#pragma unroll
            for (int nt = 0; nt < 4; nt++) s[nt] = vzero;
#pragma unroll
            for (int ks = 0; ks < 2; ks++)
#pragma unroll
                for (int nt = 0; nt < 4; nt++) {
                    bf16x8 ak = *(const bf16x8*)&Ks[(nt * 16 + lr) * ATT_STRIDE + ks * 32 + lq * 8];
                    s[nt] = mfma16x16x32(ak, bq[ks], s[nt]);
                }

            bool diag = ((it * 64) == q0);
            float tmax = -1e30f;
#pragma unroll
            for (int nt = 0; nt < 4; nt++)
#pragma unroll
                for (int r = 0; r < 4; r++) {
                    float v = s[nt][r];
                    if (diag && (nt * 16 + lq * 4 + r > qloc)) v = -1e30f;
                    s[nt][r] = v;
                    tmax = fmaxf(tmax, v);
                }
            tmax = fmaxf(tmax, __shfl_xor(tmax, 16));
            tmax = fmaxf(tmax, __shfl_xor(tmax, 32));

            float mnew = fmaxf(m_i, tmax);
            float alpha = __expf(m_i - mnew);
            float rsum = 0.f;
#pragma unroll
            for (int nt = 0; nt < 4; nt++)
#pragma unroll
                for (int r = 0; r < 4; r++) {
                    float e = __expf(s[nt][r] - mnew);
                    s[nt][r] = e;
                    rsum += e;
                }
            rsum += __shfl_xor(rsum, 16);
            rsum += __shfl_xor(rsum, 32);
            l_i = l_i * alpha + rsum;
            m_i = mnew;
#pragma unroll
            for (int dt = 0; dt < 4; dt++)
#pragma unroll
                for (int r = 0; r < 4; r++) o[dt][r] *= alpha;

            // PV: O^T[d][q] += V^T[d][key] * P^T[key][q]; two 16-key tiles per K=32 MFMA.
#pragma unroll
            for (int a = 0; a < 2; a++) {
                union { bf16x8 v; u16 hh[8]; } bp;
#pragma unroll
                for (int r = 0; r < 4; r++) {
                    bp.hh[r]     = f2bf(s[2 * a][r]);
                    bp.hh[r + 4] = f2bf(s[2 * a + 1][r]);
                }
#pragma unroll
                for (int dt = 0; dt < 4; dt++) {
                    union { bf16x8 v; uint2 u2[2]; } av;
                    const u16* vrow = &Vs[(dt * 16 + lr) * ATT_STRIDE + a * 32 + lq * 4];
                    av.u2[0] = *(const uint2*)(vrow);
                    av.u2[1] = *(const uint2*)(vrow + 16);
                    o[dt] = mfma16x16x32(av.v, bp.v, o[dt]);
                }
            }
            __syncthreads();
        }

        // epilogue: attn[q][h*64 + d], d = dt*16 + lq*4 + r -> packed 8-B stores
        float inv = 1.0f / l_i;
        int qg = q0 + qloc;
#pragma unroll
        for (int dt = 0; dt < 4; dt++) {
            union { u16 hh[4]; uint2 u2; } eo;
#pragma unroll
            for (int r = 0; r < 4; r++) eo.hh[r] = f2bf(o[dt][r] * inv);
            *(uint2*)&attn[(size_t)qg * CDIM + h * HD + dt * 16 + lq * 4] = eo.u2;
        }
    }
}

extern "C" void kernel_launch(void* const* d_in, const int* in_sizes, int n_in,
                              void* d_out, int out_size, void* d_ws, size_t ws_size,
                              hipStream_t stream) {
    const float* x    = (const float*)d_in[0];   // [4096][1024] fp32
    const float* Wqkv = (const float*)d_in[1];   // [1024][3072] fp32
    const float* bqkv = (const float*)d_in[2];   // [3072] fp32
    const float* Wout = (const float*)d_in[3];   // [1024][1024] fp32
    const float* bout = (const float*)d_in[4];   // [1024] fp32
    float* out = (float*)d_out;                  // [4096][1024] fp32

    char* ws = (char*)d_ws;
    u16* qkv   = (u16*)(ws);                     // [0, 25165824)
    u16* xb    = (u16*)(ws + 25165824);          // [25165824, 33554432) — aliases attn
    u16* attn  = xb;                             // xb dead after GEMM1
    u16* vt    = (u16*)(ws + 33554432);          // [33554432, 41943040)
    u16* wqkvt = (u16*)(ws + 41943040);          // [41943040, 48234496)
    u16* woutt = (u16*)(ws + 48234496);          // [48234496, 50331648)

    // 1. ingest: x -> bf16; weights -> B^T bf16 (biases stay fp32)
    k_cast_x<<<dim3(2048), 256, 0, stream>>>(x, xb, 524288);
    k_transpose_cast<<<dim3(96, 32), 256, 0, stream>>>(Wqkv, wqkvt, 1024, 3072);
    k_transpose_cast<<<dim3(32, 32), 256, 0, stream>>>(Wout, woutt, 1024, 1024);
    // 2. qkv = x @ Wqkv + bqkv   (bf16 out)
    k_gemm_bt<u16><<<dim3(24, 32), 256, 0, stream>>>(xb, wqkvt, bqkv, qkv, 4096, 3072, 1024);
    // 3. V^T per head
    k_transpose_v<<<dim3(128, 2, 16), 256, 0, stream>>>(qkv, vt);
    // 4. causal flash attention (S^T, paired q-tiles, register prefetch)
    k_attn<<<dim3(32, 16), 256, 0, stream>>>(qkv, vt, attn);
    // 5. out = attn @ Wout + bout   (fp32 out)
    k_gemm_bt<float><<<dim3(8, 32), 256, 0, stream>>>(attn, woutt, bout, out, 4096, 1024, 1024);
}